// Round 1
// baseline (8185.918 us; speedup 1.0000x reference)
//
#include <hip/hip_runtime.h>
#include <hip/hip_bf16.h>

#define NROWS 16384
#define XD 1024
#define DD 4096

typedef __attribute__((ext_vector_type(8))) short short8;
typedef __attribute__((ext_vector_type(4))) float f32x4;

__device__ __forceinline__ unsigned short f2bf(float f) {
  unsigned int u = __builtin_bit_cast(unsigned int, f);
  u += 0x7fffu + ((u >> 16) & 1u);
  return (unsigned short)(u >> 16);
}

// ---------------- row mask ----------------
__global__ __launch_bounds__(256) void mask_kernel(const float* __restrict__ u,
                                                   const float* __restrict__ v,
                                                   float* __restrict__ w) {
  int r = blockIdx.x;
  int t = threadIdx.x;
  const f32x4* up = (const f32x4*)(u + (size_t)r * XD);
  const f32x4* vp = (const f32x4*)(v + (size_t)r * DD);
  f32x4 a = up[t];  // 256*4 == 1024 covers the u row
  int fu = __syncthreads_or((a.x != 0.f) | (a.y != 0.f) | (a.z != 0.f) | (a.w != 0.f));
  int fv = 0;
#pragma unroll
  for (int it = 0; it < DD / (256 * 4); ++it) {
    if (!fv) {  // uniform condition -> barrier-safe
      f32x4 b = vp[it * 256 + t];
      fv = __syncthreads_or((b.x != 0.f) | (b.y != 0.f) | (b.z != 0.f) | (b.w != 0.f));
    }
  }
  if (t == 0) w[r] = (fu && fv) ? 1.f : 0.f;
}

// ---------------- k = sum(w) ----------------
__global__ __launch_bounds__(256) void ksum_kernel(const float* __restrict__ w,
                                                   float* __restrict__ kout) {
  __shared__ float sm[256];
  float s = 0.f;
  for (int i = threadIdx.x; i < NROWS; i += 256) s += w[i];
  sm[threadIdx.x] = s;
  __syncthreads();
  for (int st = 128; st > 0; st >>= 1) {
    if (threadIdx.x < st) sm[threadIdx.x] += sm[threadIdx.x + st];
    __syncthreads();
  }
  if (threadIdx.x == 0) kout[0] = sm[0];
}

// ---------------- column stats: partial sums ----------------
// grid = (cols/256, 64); each block: 256 cols x 256 rows
__global__ __launch_bounds__(256) void colstats_partial(const float* __restrict__ X, int cols,
                                                        const float* __restrict__ w,
                                                        float* __restrict__ p1,
                                                        float* __restrict__ p2) {
  int c = blockIdx.x * 256 + threadIdx.x;
  int r0 = blockIdx.y * (NROWS / 64);
  float s1 = 0.f, s2 = 0.f;
  for (int r = r0; r < r0 + NROWS / 64; ++r) {
    float wr = w[r];
    float x = X[(size_t)r * cols + c];
    float xw = x * wr;
    s1 += xw;
    s2 += xw * x;
  }
  p1[(size_t)blockIdx.y * cols + c] = s1;
  p2[(size_t)blockIdx.y * cols + c] = s2;
}

// ---------------- column stats: finalize ----------------
__global__ __launch_bounds__(256) void colstats_final(const float* __restrict__ p1,
                                                      const float* __restrict__ p2,
                                                      const float* __restrict__ kptr, int cols,
                                                      float* __restrict__ mean,
                                                      float* __restrict__ inv) {
  int c = blockIdx.x * 256 + threadIdx.x;
  float s1 = 0.f, s2 = 0.f;
  for (int j = 0; j < 64; ++j) {
    s1 += p1[(size_t)j * cols + c];
    s2 += p2[(size_t)j * cols + c];
  }
  float k = kptr[0];
  float m = s1 / k;
  float s = s2 - s1 * s1 / k;  // == sum w*(x-m)^2
  float sd = sqrtf(fmaxf(s, 0.f) / (k - 1.f));
  mean[c] = m;
  inv[c] = 1.f / (sd + 1e-7f);
}

// ---------------- GEMM1: H = relu((A - mean)*inv @ B + b1), bf16 out ----------------
// A: f32 [Mchunk][K] (chunk base), B: f32 [K][N], H: bf16 [Mchunk][N]
__global__ __launch_bounds__(256) void gemm1_kernel(const float* __restrict__ A,
                                                    const float* __restrict__ B,
                                                    const float* __restrict__ bias,
                                                    const float* __restrict__ mean,
                                                    const float* __restrict__ inv,
                                                    __hip_bfloat16* __restrict__ H,
                                                    int K, int N) {
  __shared__ char smem[32768];
  char* As = smem;           // [128 m][64 k] bf16, XOR-swizzled
  char* Bs = smem + 16384;   // [128 n][64 k] bf16 (W transposed), XOR-swizzled
  const int tid = threadIdx.x;
  const int lane = tid & 63;
  const int wave = tid >> 6;
  const int wr = wave >> 1, wc = wave & 1;
  const int m0 = blockIdx.y * 128;
  const int n0 = blockIdx.x * 128;

  f32x4 acc[4][4] = {};

  const int am = tid >> 1;          // 0..127 (row of A tile)
  const int akh = (tid & 1) * 32;   // k half
  const int bn = tid & 31;          // B: base n lane
  const int bk0 = (tid >> 5) * 8;   // B: k sub-block

  for (int k0 = 0; k0 < K; k0 += 64) {
    // ---- stage A (normalize f32 -> bf16) ----
    {
      const float* Ap = A + (size_t)(m0 + am) * K + k0 + akh;
#pragma unroll
      for (int j = 0; j < 4; ++j) {
        int kk = k0 + akh + j * 8;
        f32x4 v0 = *(const f32x4*)(Ap + j * 8);
        f32x4 v1 = *(const f32x4*)(Ap + j * 8 + 4);
        f32x4 mn0 = *(const f32x4*)(mean + kk);
        f32x4 mn1 = *(const f32x4*)(mean + kk + 4);
        f32x4 iv0 = *(const f32x4*)(inv + kk);
        f32x4 iv1 = *(const f32x4*)(inv + kk + 4);
        short8 p;
        p[0] = (short)f2bf((v0.x - mn0.x) * iv0.x);
        p[1] = (short)f2bf((v0.y - mn0.y) * iv0.y);
        p[2] = (short)f2bf((v0.z - mn0.z) * iv0.z);
        p[3] = (short)f2bf((v0.w - mn0.w) * iv0.w);
        p[4] = (short)f2bf((v1.x - mn1.x) * iv1.x);
        p[5] = (short)f2bf((v1.y - mn1.y) * iv1.y);
        p[6] = (short)f2bf((v1.z - mn1.z) * iv1.z);
        p[7] = (short)f2bf((v1.w - mn1.w) * iv1.w);
        int bo = am * 128 + ((((akh + j * 8) * 2)) ^ ((am & 7) << 4));
        *(short8*)(As + bo) = p;
      }
    }
    // ---- stage B transposed (f32 [K][N] -> bf16 [n][k]) ----
    {
#pragma unroll
      for (int jj = 0; jj < 4; ++jj) {
        int n = bn + 32 * jj;
        const float* Bp = B + (size_t)(k0 + bk0) * N + n0 + n;
        short8 p;
#pragma unroll
        for (int i = 0; i < 8; ++i) p[i] = (short)f2bf(Bp[(size_t)i * N]);
        int bo = n * 128 + ((bk0 * 2) ^ ((n & 7) << 4));
        *(short8*)(Bs + bo) = p;
      }
    }
    __syncthreads();
    // ---- compute ----
#pragma unroll
    for (int ks = 0; ks < 2; ++ks) {
      const int kb = (ks * 32 + ((lane >> 4) * 8)) * 2;
      short8 af[4], bff[4];
#pragma unroll
      for (int i = 0; i < 4; ++i) {
        int m = wr * 64 + i * 16 + (lane & 15);
        af[i] = *(const short8*)(As + m * 128 + (kb ^ ((m & 7) << 4)));
      }
#pragma unroll
      for (int j = 0; j < 4; ++j) {
        int n = wc * 64 + j * 16 + (lane & 15);
        bff[j] = *(const short8*)(Bs + n * 128 + (kb ^ ((n & 7) << 4)));
      }
#pragma unroll
      for (int i = 0; i < 4; ++i)
#pragma unroll
        for (int j = 0; j < 4; ++j)
          acc[i][j] = __builtin_amdgcn_mfma_f32_16x16x32_bf16(af[i], bff[j], acc[i][j], 0, 0, 0);
    }
    __syncthreads();
  }
  // ---- epilogue: relu(acc + bias) -> bf16 ----
#pragma unroll
  for (int i = 0; i < 4; ++i) {
    int rb = wr * 64 + i * 16 + ((lane >> 4) * 4);
#pragma unroll
    for (int j = 0; j < 4; ++j) {
      int c = wc * 64 + j * 16 + (lane & 15);
      float b = bias[n0 + c];
#pragma unroll
      for (int r = 0; r < 4; ++r) {
        float val = fmaxf(acc[i][j][r] + b, 0.f);
        ((unsigned short*)H)[(size_t)(m0 + rb + r) * N + n0 + c] = f2bf(val);
      }
    }
  }
}

// ---------------- GEMM2: Out = (H @ B + b2) * w, f32 out ----------------
// A: bf16 [Mchunk][K], B: f32 [K][N], Out: f32 [Mchunk][N] (chunk base), wrow: chunk base
__global__ __launch_bounds__(256) void gemm2_kernel(const __hip_bfloat16* __restrict__ Abf,
                                                    const float* __restrict__ B,
                                                    const float* __restrict__ bias,
                                                    const float* __restrict__ wrow,
                                                    float* __restrict__ Out,
                                                    int K, int N) {
  __shared__ char smem[32768];
  char* As = smem;
  char* Bs = smem + 16384;
  const int tid = threadIdx.x;
  const int lane = tid & 63;
  const int wave = tid >> 6;
  const int wr = wave >> 1, wc = wave & 1;
  const int m0 = blockIdx.y * 128;
  const int n0 = blockIdx.x * 128;

  f32x4 acc[4][4] = {};

  const int am = tid >> 1;
  const int akh = (tid & 1) * 32;
  const int bn = tid & 31;
  const int bk0 = (tid >> 5) * 8;

  for (int k0 = 0; k0 < K; k0 += 64) {
    // ---- stage A (bf16 direct copy, 16B chunks) ----
    {
      const unsigned short* Ap = (const unsigned short*)Abf + (size_t)(m0 + am) * K + k0 + akh;
#pragma unroll
      for (int j = 0; j < 4; ++j) {
        short8 p = *(const short8*)(Ap + j * 8);
        int bo = am * 128 + ((((akh + j * 8) * 2)) ^ ((am & 7) << 4));
        *(short8*)(As + bo) = p;
      }
    }
    // ---- stage B transposed ----
    {
#pragma unroll
      for (int jj = 0; jj < 4; ++jj) {
        int n = bn + 32 * jj;
        const float* Bp = B + (size_t)(k0 + bk0) * N + n0 + n;
        short8 p;
#pragma unroll
        for (int i = 0; i < 8; ++i) p[i] = (short)f2bf(Bp[(size_t)i * N]);
        int bo = n * 128 + ((bk0 * 2) ^ ((n & 7) << 4));
        *(short8*)(Bs + bo) = p;
      }
    }
    __syncthreads();
#pragma unroll
    for (int ks = 0; ks < 2; ++ks) {
      const int kb = (ks * 32 + ((lane >> 4) * 8)) * 2;
      short8 af[4], bff[4];
#pragma unroll
      for (int i = 0; i < 4; ++i) {
        int m = wr * 64 + i * 16 + (lane & 15);
        af[i] = *(const short8*)(As + m * 128 + (kb ^ ((m & 7) << 4)));
      }
#pragma unroll
      for (int j = 0; j < 4; ++j) {
        int n = wc * 64 + j * 16 + (lane & 15);
        bff[j] = *(const short8*)(Bs + n * 128 + (kb ^ ((n & 7) << 4)));
      }
#pragma unroll
      for (int i = 0; i < 4; ++i)
#pragma unroll
        for (int j = 0; j < 4; ++j)
          acc[i][j] = __builtin_amdgcn_mfma_f32_16x16x32_bf16(af[i], bff[j], acc[i][j], 0, 0, 0);
    }
    __syncthreads();
  }
  // ---- epilogue: (acc + bias) * w[row] -> f32 ----
#pragma unroll
  for (int i = 0; i < 4; ++i) {
    int rb = wr * 64 + i * 16 + ((lane >> 4) * 4);
#pragma unroll
    for (int j = 0; j < 4; ++j) {
      int c = wc * 64 + j * 16 + (lane & 15);
      float b = bias[n0 + c];
#pragma unroll
      for (int r = 0; r < 4; ++r) {
        int row = m0 + rb + r;
        float val = (acc[i][j][r] + b) * wrow[row];
        Out[(size_t)row * N + n0 + c] = val;
      }
    }
  }
}

extern "C" void kernel_launch(void* const* d_in, const int* in_sizes, int n_in,
                              void* d_out, int out_size, void* d_ws, size_t ws_size,
                              hipStream_t stream) {
  const float* u    = (const float*)d_in[0];
  const float* v    = (const float*)d_in[1];
  const float* u_W1 = (const float*)d_in[2];
  const float* u_b1 = (const float*)d_in[3];
  const float* u_W2 = (const float*)d_in[4];
  const float* u_b2 = (const float*)d_in[5];
  const float* v_W1 = (const float*)d_in[6];
  const float* v_b1 = (const float*)d_in[7];
  const float* v_W2 = (const float*)d_in[8];
  const float* v_b2 = (const float*)d_in[9];
  float* out1 = (float*)d_out;
  float* out2 = out1 + (size_t)NROWS * XD;

  float* wsf = (float*)d_ws;
  size_t off = 0;
  float* w_     = wsf + off; off += NROWS;
  float* kv     = wsf + off; off += 16;
  float* u_mean = wsf + off; off += XD;
  float* u_inv  = wsf + off; off += XD;
  float* v_mean = wsf + off; off += DD;
  float* v_inv  = wsf + off; off += DD;
  float* p1u    = wsf + off; off += 64 * XD;
  float* p2u    = wsf + off; off += 64 * XD;
  float* p1v    = wsf + off; off += 64 * DD;
  float* p2v    = wsf + off; off += 64 * DD;
  size_t hid_off = (off * 4 + 255) & ~(size_t)255;
  __hip_bfloat16* hid = (__hip_bfloat16*)((char*)d_ws + hid_off);

  // pick the largest row-chunk whose v-hidden (CH x 8192 bf16) fits in ws
  int CH = 2048;
  while (CH > 256 && hid_off + (size_t)CH * (2 * DD) * 2 > ws_size) CH >>= 1;

  mask_kernel<<<NROWS, 256, 0, stream>>>(u, v, w_);
  ksum_kernel<<<1, 256, 0, stream>>>(w_, kv);
  colstats_partial<<<dim3(XD / 256, 64), 256, 0, stream>>>(u, XD, w_, p1u, p2u);
  colstats_partial<<<dim3(DD / 256, 64), 256, 0, stream>>>(v, DD, w_, p1v, p2v);
  colstats_final<<<XD / 256, 256, 0, stream>>>(p1u, p2u, kv, XD, u_mean, u_inv);
  colstats_final<<<DD / 256, 256, 0, stream>>>(p1v, p2v, kv, DD, v_mean, v_inv);

  for (int r0 = 0; r0 < NROWS; r0 += CH) {
    gemm1_kernel<<<dim3((2 * XD) / 128, CH / 128), 256, 0, stream>>>(
        u + (size_t)r0 * XD, u_W1, u_b1, u_mean, u_inv, hid, XD, 2 * XD);
    gemm2_kernel<<<dim3(XD / 128, CH / 128), 256, 0, stream>>>(
        hid, u_W2, u_b2, w_ + r0, out1 + (size_t)r0 * XD, 2 * XD, XD);
    gemm1_kernel<<<dim3((2 * DD) / 128, CH / 128), 256, 0, stream>>>(
        v + (size_t)r0 * DD, v_W1, v_b1, v_mean, v_inv, hid, DD, 2 * DD);
    gemm2_kernel<<<dim3(DD / 128, CH / 128), 256, 0, stream>>>(
        hid, v_W2, v_b2, w_ + r0, out2 + (size_t)r0 * DD, 2 * DD, DD);
  }
}

// Round 2
// 4764.061 us; speedup vs baseline: 1.7183x; 1.7183x over previous
//
#include <hip/hip_runtime.h>
#include <hip/hip_bf16.h>

#define NROWS 16384
#define XD 1024
#define DD 4096

typedef __attribute__((ext_vector_type(8))) short short8;
typedef __attribute__((ext_vector_type(4))) float f32x4;

__device__ __forceinline__ unsigned short f2bf(float f) {
  unsigned int u = __builtin_bit_cast(unsigned int, f);
  u += 0x7fffu + ((u >> 16) & 1u);
  return (unsigned short)(u >> 16);
}

__device__ __forceinline__ void load_lds16(const void* g, void* l) {
  __builtin_amdgcn_global_load_lds((const __attribute__((address_space(1))) void*)g,
                                   (__attribute__((address_space(3))) void*)l, 16, 0, 0);
}

// ---------------- row mask ----------------
__global__ __launch_bounds__(256) void mask_kernel(const float* __restrict__ u,
                                                   const float* __restrict__ v,
                                                   float* __restrict__ w) {
  int r = blockIdx.x;
  int t = threadIdx.x;
  const f32x4* up = (const f32x4*)(u + (size_t)r * XD);
  const f32x4* vp = (const f32x4*)(v + (size_t)r * DD);
  f32x4 a = up[t];
  int fu = __syncthreads_or((a.x != 0.f) | (a.y != 0.f) | (a.z != 0.f) | (a.w != 0.f));
  int fv = 0;
#pragma unroll
  for (int it = 0; it < DD / (256 * 4); ++it) {
    if (!fv) {
      f32x4 b = vp[it * 256 + t];
      fv = __syncthreads_or((b.x != 0.f) | (b.y != 0.f) | (b.z != 0.f) | (b.w != 0.f));
    }
  }
  if (t == 0) w[r] = (fu && fv) ? 1.f : 0.f;
}

// ---------------- k = sum(w) ----------------
__global__ __launch_bounds__(256) void ksum_kernel(const float* __restrict__ w,
                                                   float* __restrict__ kout) {
  __shared__ float sm[256];
  float s = 0.f;
  for (int i = threadIdx.x; i < NROWS; i += 256) s += w[i];
  sm[threadIdx.x] = s;
  __syncthreads();
  for (int st = 128; st > 0; st >>= 1) {
    if (threadIdx.x < st) sm[threadIdx.x] += sm[threadIdx.x + st];
    __syncthreads();
  }
  if (threadIdx.x == 0) kout[0] = sm[0];
}

// ---------------- column stats ----------------
__global__ __launch_bounds__(256) void colstats_partial(const float* __restrict__ X, int cols,
                                                        const float* __restrict__ w,
                                                        float* __restrict__ p1,
                                                        float* __restrict__ p2) {
  int c = blockIdx.x * 256 + threadIdx.x;
  int r0 = blockIdx.y * (NROWS / 64);
  float s1 = 0.f, s2 = 0.f;
  for (int r = r0; r < r0 + NROWS / 64; ++r) {
    float wr = w[r];
    float x = X[(size_t)r * cols + c];
    float xw = x * wr;
    s1 += xw;
    s2 += xw * x;
  }
  p1[(size_t)blockIdx.y * cols + c] = s1;
  p2[(size_t)blockIdx.y * cols + c] = s2;
}

__global__ __launch_bounds__(256) void colstats_final(const float* __restrict__ p1,
                                                      const float* __restrict__ p2,
                                                      const float* __restrict__ kptr, int cols,
                                                      float* __restrict__ mean,
                                                      float* __restrict__ inv) {
  int c = blockIdx.x * 256 + threadIdx.x;
  float s1 = 0.f, s2 = 0.f;
  for (int j = 0; j < 64; ++j) {
    s1 += p1[(size_t)j * cols + c];
    s2 += p2[(size_t)j * cols + c];
  }
  float k = kptr[0];
  float m = s1 / k;
  float s = s2 - s1 * s1 / k;
  float sd = sqrtf(fmaxf(s, 0.f) / (k - 1.f));
  mean[c] = m;
  inv[c] = 1.f / (sd + 1e-7f);
}

// ---------------- weight transpose+convert: W[R][C] f32 -> T[C][R] bf16 ----------------
__global__ __launch_bounds__(256) void wt_kernel(const float* __restrict__ W, int R, int C,
                                                 unsigned short* __restrict__ T) {
  __shared__ unsigned short tile[64][65];
  int r0 = blockIdx.x * 64, c0 = blockIdx.y * 64;
  int tr = threadIdx.x >> 2;
  int tc = (threadIdx.x & 3) * 16;
  const float* src = W + (size_t)(r0 + tr) * C + c0 + tc;
#pragma unroll
  for (int i = 0; i < 16; i += 4) {
    f32x4 v4 = *(const f32x4*)(src + i);
    tile[tr][tc + i + 0] = f2bf(v4.x);
    tile[tr][tc + i + 1] = f2bf(v4.y);
    tile[tr][tc + i + 2] = f2bf(v4.z);
    tile[tr][tc + i + 3] = f2bf(v4.w);
  }
  __syncthreads();
  unsigned short* dst = T + (size_t)(c0 + tr) * R + r0 + tc;
  short8 o0, o1;
#pragma unroll
  for (int i = 0; i < 8; ++i) o0[i] = (short)tile[tc + i][tr];
#pragma unroll
  for (int i = 0; i < 8; ++i) o1[i] = (short)tile[tc + 8 + i][tr];
  *(short8*)(dst) = o0;
  *(short8*)(dst + 8) = o1;
}

// ---------------- GEMM1: H = relu(((A-mean)*inv) @ Bt^T + b1), bf16 out ----------------
// A: f32 [Mchunk][K] k-contig; Bt: bf16 [N][K] k-contig; H: bf16 [Mchunk][N]
__global__ __launch_bounds__(256) void gemm1_kernel(const float* __restrict__ A,
                                                    const unsigned short* __restrict__ Bt,
                                                    const float* __restrict__ bias,
                                                    const float* __restrict__ mean,
                                                    const float* __restrict__ inv,
                                                    unsigned short* __restrict__ H,
                                                    int K, int N) {
  __shared__ char smem[32768];
  char* As = smem;          // [128 m][64 k] bf16 linear
  char* Bs = smem + 16384;  // [128 n][64 k] bf16 linear
  const int tid = threadIdx.x;
  const int lane = tid & 63;
  const int wave = tid >> 6;
  const int wr = wave >> 1, wc = wave & 1;

  // XCD-aware bijective swizzle (all grids here have nwg % 8 == 0)
  int nbx = gridDim.x;
  int nwg = nbx * gridDim.y;
  int bid = blockIdx.y * nbx + blockIdx.x;
  int sw = (bid & 7) * (nwg >> 3) + (bid >> 3);
  const int m0 = (sw / nbx) * 128;
  const int n0 = (sw % nbx) * 128;

  f32x4 acc[4][4] = {};

  const int arow = tid >> 3;       // 0..31
  const int acol = (tid & 7) * 8;  // f32/bf16 col within 64

  for (int k0 = 0; k0 < K; k0 += 64) {
    // ---- B: global_load_lds, 4 chunks/wave, 1KB each ----
#pragma unroll
    for (int it = 0; it < 4; ++it) {
      int c = wave * 4 + it;
      const unsigned short* src =
          Bt + (size_t)(n0 + c * 8 + (lane >> 3)) * K + k0 + (lane & 7) * 8;
      load_lds16(src, Bs + c * 1024);
    }
    // ---- A: normalize f32 -> bf16, linear ds_write_b128 ----
    {
      int kk = k0 + acol;
      f32x4 mn0 = *(const f32x4*)(mean + kk);
      f32x4 mn1 = *(const f32x4*)(mean + kk + 4);
      f32x4 iv0 = *(const f32x4*)(inv + kk);
      f32x4 iv1 = *(const f32x4*)(inv + kk + 4);
#pragma unroll
      for (int it = 0; it < 4; ++it) {
        int row = arow + it * 32;
        const float* src = A + (size_t)(m0 + row) * K + k0 + acol;
        f32x4 v0 = *(const f32x4*)(src);
        f32x4 v1 = *(const f32x4*)(src + 4);
        short8 p;
        p[0] = (short)f2bf((v0.x - mn0.x) * iv0.x);
        p[1] = (short)f2bf((v0.y - mn0.y) * iv0.y);
        p[2] = (short)f2bf((v0.z - mn0.z) * iv0.z);
        p[3] = (short)f2bf((v0.w - mn0.w) * iv0.w);
        p[4] = (short)f2bf((v1.x - mn1.x) * iv1.x);
        p[5] = (short)f2bf((v1.y - mn1.y) * iv1.y);
        p[6] = (short)f2bf((v1.z - mn1.z) * iv1.z);
        p[7] = (short)f2bf((v1.w - mn1.w) * iv1.w);
        *(short8*)(As + row * 128 + acol * 2) = p;
      }
    }
    __syncthreads();
#pragma unroll
    for (int ks = 0; ks < 2; ++ks) {
      const int kb = (ks * 32 + ((lane >> 4) * 8)) * 2;
      short8 af[4], bf_[4];
#pragma unroll
      for (int i = 0; i < 4; ++i) {
        int m = wr * 64 + i * 16 + (lane & 15);
        af[i] = *(const short8*)(As + m * 128 + kb);
      }
#pragma unroll
      for (int j = 0; j < 4; ++j) {
        int n = wc * 64 + j * 16 + (lane & 15);
        bf_[j] = *(const short8*)(Bs + n * 128 + kb);
      }
#pragma unroll
      for (int i = 0; i < 4; ++i)
#pragma unroll
        for (int j = 0; j < 4; ++j)
          acc[i][j] = __builtin_amdgcn_mfma_f32_16x16x32_bf16(af[i], bf_[j], acc[i][j], 0, 0, 0);
    }
    __syncthreads();
  }
#pragma unroll
  for (int i = 0; i < 4; ++i) {
    int rb = wr * 64 + i * 16 + ((lane >> 4) * 4);
#pragma unroll
    for (int j = 0; j < 4; ++j) {
      int c = wc * 64 + j * 16 + (lane & 15);
      float b = bias[n0 + c];
#pragma unroll
      for (int r = 0; r < 4; ++r) {
        float val = fmaxf(acc[i][j][r] + b, 0.f);
        H[(size_t)(m0 + rb + r) * N + n0 + c] = f2bf(val);
      }
    }
  }
}

// ---------------- GEMM2: Out = (H @ Bt^T + b2) * w, f32 out ----------------
// A: bf16 [Mchunk][K]; Bt: bf16 [N][K]; Out f32
__global__ __launch_bounds__(256) void gemm2_kernel(const unsigned short* __restrict__ Abf,
                                                    const unsigned short* __restrict__ Bt,
                                                    const float* __restrict__ bias,
                                                    const float* __restrict__ wrow,
                                                    float* __restrict__ Out,
                                                    int K, int N) {
  __shared__ char smem[32768];
  char* As = smem;
  char* Bs = smem + 16384;
  const int tid = threadIdx.x;
  const int lane = tid & 63;
  const int wave = tid >> 6;
  const int wr = wave >> 1, wc = wave & 1;

  int nbx = gridDim.x;
  int nwg = nbx * gridDim.y;
  int bid = blockIdx.y * nbx + blockIdx.x;
  int sw = (bid & 7) * (nwg >> 3) + (bid >> 3);
  const int m0 = (sw / nbx) * 128;
  const int n0 = (sw % nbx) * 128;

  f32x4 acc[4][4] = {};

  for (int k0 = 0; k0 < K; k0 += 64) {
#pragma unroll
    for (int it = 0; it < 4; ++it) {
      int c = wave * 4 + it;
      const unsigned short* asrc =
          Abf + (size_t)(m0 + c * 8 + (lane >> 3)) * K + k0 + (lane & 7) * 8;
      load_lds16(asrc, As + c * 1024);
      const unsigned short* bsrc =
          Bt + (size_t)(n0 + c * 8 + (lane >> 3)) * K + k0 + (lane & 7) * 8;
      load_lds16(bsrc, Bs + c * 1024);
    }
    __syncthreads();
#pragma unroll
    for (int ks = 0; ks < 2; ++ks) {
      const int kb = (ks * 32 + ((lane >> 4) * 8)) * 2;
      short8 af[4], bf_[4];
#pragma unroll
      for (int i = 0; i < 4; ++i) {
        int m = wr * 64 + i * 16 + (lane & 15);
        af[i] = *(const short8*)(As + m * 128 + kb);
      }
#pragma unroll
      for (int j = 0; j < 4; ++j) {
        int n = wc * 64 + j * 16 + (lane & 15);
        bf_[j] = *(const short8*)(Bs + n * 128 + kb);
      }
#pragma unroll
      for (int i = 0; i < 4; ++i)
#pragma unroll
        for (int j = 0; j < 4; ++j)
          acc[i][j] = __builtin_amdgcn_mfma_f32_16x16x32_bf16(af[i], bf_[j], acc[i][j], 0, 0, 0);
    }
    __syncthreads();
  }
#pragma unroll
  for (int i = 0; i < 4; ++i) {
    int rb = wr * 64 + i * 16 + ((lane >> 4) * 4);
#pragma unroll
    for (int j = 0; j < 4; ++j) {
      int c = wc * 64 + j * 16 + (lane & 15);
      float b = bias[n0 + c];
#pragma unroll
      for (int r = 0; r < 4; ++r) {
        int row = m0 + rb + r;
        float val = (acc[i][j][r] + b) * wrow[row];
        Out[(size_t)row * N + n0 + c] = val;
      }
    }
  }
}

extern "C" void kernel_launch(void* const* d_in, const int* in_sizes, int n_in,
                              void* d_out, int out_size, void* d_ws, size_t ws_size,
                              hipStream_t stream) {
  const float* u    = (const float*)d_in[0];
  const float* v    = (const float*)d_in[1];
  const float* u_W1 = (const float*)d_in[2];
  const float* u_b1 = (const float*)d_in[3];
  const float* u_W2 = (const float*)d_in[4];
  const float* u_b2 = (const float*)d_in[5];
  const float* v_W1 = (const float*)d_in[6];
  const float* v_b1 = (const float*)d_in[7];
  const float* v_W2 = (const float*)d_in[8];
  const float* v_b2 = (const float*)d_in[9];
  float* out1 = (float*)d_out;
  float* out2 = out1 + (size_t)NROWS * XD;

  float* wsf = (float*)d_ws;
  size_t off = 0;
  float* w_     = wsf + off; off += NROWS;
  float* kv     = wsf + off; off += 16;
  float* u_mean = wsf + off; off += XD;
  float* u_inv  = wsf + off; off += XD;
  float* v_mean = wsf + off; off += DD;
  float* v_inv  = wsf + off; off += DD;
  float* p1u    = wsf + off; off += 64 * XD;
  float* p2u    = wsf + off; off += 64 * XD;
  float* p1v    = wsf + off; off += 64 * DD;
  float* p2v    = wsf + off; off += 64 * DD;

  size_t boff = (off * 4 + 255) & ~(size_t)255;  // byte offset, 256B aligned
  unsigned short* W1Tu = (unsigned short*)((char*)d_ws + boff); boff += (size_t)(2 * XD) * XD * 2;
  unsigned short* W2Tu = (unsigned short*)((char*)d_ws + boff); boff += (size_t)XD * (2 * XD) * 2;
  unsigned short* W1Tv = (unsigned short*)((char*)d_ws + boff); boff += (size_t)(2 * DD) * DD * 2;
  unsigned short* W2Tv = (unsigned short*)((char*)d_ws + boff); boff += (size_t)DD * (2 * DD) * 2;
  size_t hid_off = (boff + 255) & ~(size_t)255;
  unsigned short* hid = (unsigned short*)((char*)d_ws + hid_off);

  int CH = 2048;
  while (CH > 128 && hid_off + (size_t)CH * (2 * DD) * 2 > ws_size) CH >>= 1;

  mask_kernel<<<NROWS, 256, 0, stream>>>(u, v, w_);
  ksum_kernel<<<1, 256, 0, stream>>>(w_, kv);
  colstats_partial<<<dim3(XD / 256, 64), 256, 0, stream>>>(u, XD, w_, p1u, p2u);
  colstats_partial<<<dim3(DD / 256, 64), 256, 0, stream>>>(v, DD, w_, p1v, p2v);
  colstats_final<<<XD / 256, 256, 0, stream>>>(p1u, p2u, kv, XD, u_mean, u_inv);
  colstats_final<<<DD / 256, 256, 0, stream>>>(p1v, p2v, kv, DD, v_mean, v_inv);

  // weight transpose+convert: W[R][C] -> T[C][R] bf16
  wt_kernel<<<dim3(XD / 64, (2 * XD) / 64), 256, 0, stream>>>(u_W1, XD, 2 * XD, W1Tu);
  wt_kernel<<<dim3((2 * XD) / 64, XD / 64), 256, 0, stream>>>(u_W2, 2 * XD, XD, W2Tu);
  wt_kernel<<<dim3(DD / 64, (2 * DD) / 64), 256, 0, stream>>>(v_W1, DD, 2 * DD, W1Tv);
  wt_kernel<<<dim3((2 * DD) / 64, DD / 64), 256, 0, stream>>>(v_W2, 2 * DD, DD, W2Tv);

  for (int r0 = 0; r0 < NROWS; r0 += CH) {
    gemm1_kernel<<<dim3((2 * XD) / 128, CH / 128), 256, 0, stream>>>(
        u + (size_t)r0 * XD, W1Tu, u_b1, u_mean, u_inv, hid, XD, 2 * XD);
    gemm2_kernel<<<dim3(XD / 128, CH / 128), 256, 0, stream>>>(
        hid, W2Tu, u_b2, w_ + r0, out1 + (size_t)r0 * XD, 2 * XD, XD);
    gemm1_kernel<<<dim3((2 * DD) / 128, CH / 128), 256, 0, stream>>>(
        v + (size_t)r0 * DD, W1Tv, v_b1, v_mean, v_inv, hid, DD, 2 * DD);
    gemm2_kernel<<<dim3(DD / 128, CH / 128), 256, 0, stream>>>(
        hid, W2Tv, v_b2, w_ + r0, out2 + (size_t)r0 * DD, 2 * DD, DD);
  }
}

// Round 3
// 2372.919 us; speedup vs baseline: 3.4497x; 2.0077x over previous
//
#include <hip/hip_runtime.h>
#include <hip/hip_bf16.h>

#define NROWS 16384
#define XD 1024
#define DD 4096

typedef __attribute__((ext_vector_type(8))) short short8;
typedef __attribute__((ext_vector_type(4))) float f32x4;

__device__ __forceinline__ unsigned short f2bf(float f) {
  unsigned int u = __builtin_bit_cast(unsigned int, f);
  u += 0x7fffu + ((u >> 16) & 1u);
  return (unsigned short)(u >> 16);
}

__device__ __forceinline__ void load_lds16(const void* g, void* l) {
  __builtin_amdgcn_global_load_lds((const __attribute__((address_space(1))) void*)g,
                                   (__attribute__((address_space(3))) void*)l, 16, 0, 0);
}

// ---------------- row mask ----------------
__global__ __launch_bounds__(256) void mask_kernel(const float* __restrict__ u,
                                                   const float* __restrict__ v,
                                                   float* __restrict__ w) {
  int r = blockIdx.x;
  int t = threadIdx.x;
  const f32x4* up = (const f32x4*)(u + (size_t)r * XD);
  const f32x4* vp = (const f32x4*)(v + (size_t)r * DD);
  f32x4 a = up[t];
  int fu = __syncthreads_or((a.x != 0.f) | (a.y != 0.f) | (a.z != 0.f) | (a.w != 0.f));
  int fv = 0;
#pragma unroll
  for (int it = 0; it < DD / (256 * 4); ++it) {
    if (!fv) {
      f32x4 b = vp[it * 256 + t];
      fv = __syncthreads_or((b.x != 0.f) | (b.y != 0.f) | (b.z != 0.f) | (b.w != 0.f));
    }
  }
  if (t == 0) w[r] = (fu && fv) ? 1.f : 0.f;
}

// ---------------- k = sum(w) ----------------
__global__ __launch_bounds__(256) void ksum_kernel(const float* __restrict__ w,
                                                   float* __restrict__ kout) {
  __shared__ float sm[256];
  float s = 0.f;
  for (int i = threadIdx.x; i < NROWS; i += 256) s += w[i];
  sm[threadIdx.x] = s;
  __syncthreads();
  for (int st = 128; st > 0; st >>= 1) {
    if (threadIdx.x < st) sm[threadIdx.x] += sm[threadIdx.x + st];
    __syncthreads();
  }
  if (threadIdx.x == 0) kout[0] = sm[0];
}

// ---------------- column stats ----------------
__global__ __launch_bounds__(256) void colstats_partial(const float* __restrict__ X, int cols,
                                                        const float* __restrict__ w,
                                                        float* __restrict__ p1,
                                                        float* __restrict__ p2) {
  int c = blockIdx.x * 256 + threadIdx.x;
  int r0 = blockIdx.y * (NROWS / 64);
  float s1 = 0.f, s2 = 0.f;
  for (int r = r0; r < r0 + NROWS / 64; ++r) {
    float wr = w[r];
    float x = X[(size_t)r * cols + c];
    float xw = x * wr;
    s1 += xw;
    s2 += xw * x;
  }
  p1[(size_t)blockIdx.y * cols + c] = s1;
  p2[(size_t)blockIdx.y * cols + c] = s2;
}

__global__ __launch_bounds__(256) void colstats_final(const float* __restrict__ p1,
                                                      const float* __restrict__ p2,
                                                      const float* __restrict__ kptr, int cols,
                                                      float* __restrict__ mean,
                                                      float* __restrict__ inv) {
  int c = blockIdx.x * 256 + threadIdx.x;
  float s1 = 0.f, s2 = 0.f;
  for (int j = 0; j < 64; ++j) {
    s1 += p1[(size_t)j * cols + c];
    s2 += p2[(size_t)j * cols + c];
  }
  float k = kptr[0];
  float m = s1 / k;
  float s = s2 - s1 * s1 / k;
  float sd = sqrtf(fmaxf(s, 0.f) / (k - 1.f));
  mean[c] = m;
  inv[c] = 1.f / (sd + 1e-7f);
}

// ---------------- weight transpose+convert: W[R][C] f32 -> T[C][R] bf16 ----------------
__global__ __launch_bounds__(256) void wt_kernel(const float* __restrict__ W, int R, int C,
                                                 unsigned short* __restrict__ T) {
  __shared__ unsigned short tile[64][65];
  int r0 = blockIdx.x * 64, c0 = blockIdx.y * 64;
  int tr = threadIdx.x >> 2;
  int tc = (threadIdx.x & 3) * 16;
  const float* src = W + (size_t)(r0 + tr) * C + c0 + tc;
#pragma unroll
  for (int i = 0; i < 16; i += 4) {
    f32x4 v4 = *(const f32x4*)(src + i);
    tile[tr][tc + i + 0] = f2bf(v4.x);
    tile[tr][tc + i + 1] = f2bf(v4.y);
    tile[tr][tc + i + 2] = f2bf(v4.z);
    tile[tr][tc + i + 3] = f2bf(v4.w);
  }
  __syncthreads();
  unsigned short* dst = T + (size_t)(c0 + tr) * R + r0 + tc;
  short8 o0, o1;
#pragma unroll
  for (int i = 0; i < 8; ++i) o0[i] = (short)tile[tc + i][tr];
#pragma unroll
  for (int i = 0; i < 8; ++i) o1[i] = (short)tile[tc + 8 + i][tr];
  *(short8*)(dst) = o0;
  *(short8*)(dst + 8) = o1;
}

// ---------------- normalize chunk: bf16 out ----------------
__global__ __launch_bounds__(256) void norm_kernel(const float* __restrict__ X,
                                                   const float* __restrict__ mean,
                                                   const float* __restrict__ inv,
                                                   unsigned short* __restrict__ O,
                                                   int colmask, size_t n8) {
  size_t stride = (size_t)gridDim.x * 256;
  for (size_t i = (size_t)blockIdx.x * 256 + threadIdx.x; i < n8; i += stride) {
    int c8 = (int)(i & (size_t)colmask);
    const float* xp = X + i * 8;
    f32x4 a = *(const f32x4*)xp;
    f32x4 b = *(const f32x4*)(xp + 4);
    f32x4 m0 = *(const f32x4*)(mean + c8 * 8);
    f32x4 m1 = *(const f32x4*)(mean + c8 * 8 + 4);
    f32x4 i0 = *(const f32x4*)(inv + c8 * 8);
    f32x4 i1 = *(const f32x4*)(inv + c8 * 8 + 4);
    short8 p;
    p[0] = (short)f2bf((a.x - m0.x) * i0.x);
    p[1] = (short)f2bf((a.y - m0.y) * i0.y);
    p[2] = (short)f2bf((a.z - m0.z) * i0.z);
    p[3] = (short)f2bf((a.w - m0.w) * i0.w);
    p[4] = (short)f2bf((b.x - m1.x) * i1.x);
    p[5] = (short)f2bf((b.y - m1.y) * i1.y);
    p[6] = (short)f2bf((b.z - m1.z) * i1.z);
    p[7] = (short)f2bf((b.w - m1.w) * i1.w);
    *(short8*)(O + i * 8) = p;
  }
}

// ---------------- 256x256 tiled GEMM, BK=64, 8 waves, dbuf LDS, swizzled ----------------
// C[M][N] = A[M][K] (bf16, k-contig) x Bt[N][K]^T (bf16, k-contig)
// EPI 0: H = relu(C + bias) -> bf16 ;  EPI 1: O = (C + bias) * wrow -> f32
template <int EPI>
__global__ __launch_bounds__(512, 2) void gemm8p(const unsigned short* __restrict__ A,
                                                 const unsigned short* __restrict__ Bt,
                                                 const float* __restrict__ bias,
                                                 const float* __restrict__ wrow,
                                                 void* __restrict__ OutP,
                                                 int N, int K) {
  __shared__ char lds[131072];  // A: [2][256][64]bf16 @0, B: same @65536
  const int tid = threadIdx.x;
  const int lane = tid & 63;
  const int wave = tid >> 6;     // 0..7
  const int wr = wave >> 2;      // 0..1 (m half)
  const int wc = wave & 3;       // 0..3 (n quarter)

  const int gn = N >> 8;
  const int nwg = gridDim.x;
  const int bid = blockIdx.x;
  const int sw = (nwg & 7) ? bid : ((bid & 7) * (nwg >> 3) + (bid >> 3));
  const int m0 = (sw / gn) << 8;
  const int n0 = (sw % gn) << 8;

  // staging: chunk ca = i*8+wave covers rows ca*8..ca*8+7; source col pre-swizzled
  const int srow = lane >> 3;
  const int scol = ((lane & 7) ^ srow) << 3;

  const int NT = K >> 6;
  f32x4 acc[8][4] = {};

  char* const Abase = lds + wr * 16384;
  char* const Bbase = lds + 65536 + (wc >> 1) * 16384;
  const int bcol = (wc & 1) * 64;
  const int fr = lane & 15;             // row/col within fragment
  const int kbyte = (lane >> 4) << 4;   // k byte offset within 64B half

#define STAGE(T, BUF)                                                              \
  {                                                                                \
    const int k0_ = (T) << 6;                                                      \
    _Pragma("unroll") for (int i = 0; i < 4; ++i) {                                \
      const int row_ = i * 64 + wave * 8 + srow;                                   \
      const int co_ = (i * 8 + wave) * 1024;                                       \
      load_lds16(A + (size_t)(m0 + row_) * K + k0_ + scol, lds + (BUF)*32768 + co_); \
      load_lds16(Bt + (size_t)(n0 + row_) * K + k0_ + scol,                        \
                 lds + 65536 + (BUF)*32768 + co_);                                 \
    }                                                                              \
  }

  STAGE(0, 0);
  __syncthreads();

  for (int t = 0; t < NT; ++t) {
    const int buf = t & 1;
    const int ab = buf * 32768;
    if (t + 1 < NT) STAGE(t + 1, buf ^ 1);

    // B fragments: 4 n-frags x 2 k-steps
    short8 bfr[2][4];
#pragma unroll
    for (int s = 0; s < 2; ++s)
#pragma unroll
      for (int g = 0; g < 4; ++g) {
        const int r = bcol + g * 16 + fr;
        const int kb = s * 64 + kbyte;
        bfr[s][g] = *(const short8*)(Bbase + ab + r * 128 + (kb ^ ((r & 7) << 4)));
      }

    // A fragments ping-pong: pairs of 2 m-frags, prefetched one quadrant ahead
    short8 afA[2][2], afB[2][2];
#pragma unroll
    for (int p = 0; p < 2; ++p)
#pragma unroll
      for (int s = 0; s < 2; ++s) {
        const int r = p * 16 + fr;
        const int kb = s * 64 + kbyte;
        afA[p][s] = *(const short8*)(Abase + ab + r * 128 + (kb ^ ((r & 7) << 4)));
      }
#pragma unroll
    for (int q = 0; q < 4; ++q) {
      if (q < 3) {
#pragma unroll
        for (int p = 0; p < 2; ++p)
#pragma unroll
          for (int s = 0; s < 2; ++s) {
            const int r = ((q + 1) * 2 + p) * 16 + fr;
            const int kb = s * 64 + kbyte;
            short8 vf = *(const short8*)(Abase + ab + r * 128 + (kb ^ ((r & 7) << 4)));
            if (q & 1) afA[p][s] = vf; else afB[p][s] = vf;
          }
      }
      __builtin_amdgcn_s_setprio(1);
#pragma unroll
      for (int p = 0; p < 2; ++p)
#pragma unroll
        for (int s = 0; s < 2; ++s)
#pragma unroll
          for (int g = 0; g < 4; ++g) {
            const short8 av = (q & 1) ? afB[p][s] : afA[p][s];
            acc[q * 2 + p][g] =
                __builtin_amdgcn_mfma_f32_16x16x32_bf16(av, bfr[s][g], acc[q * 2 + p][g], 0, 0, 0);
          }
      __builtin_amdgcn_s_setprio(0);
    }
    __syncthreads();
  }

  const int colloc = wc * 64 + fr;
  const int rowb = wr * 128 + ((lane >> 4) << 2);
  if (EPI == 0) {
    unsigned short* H = (unsigned short*)OutP;
#pragma unroll
    for (int f = 0; f < 8; ++f)
#pragma unroll
      for (int g = 0; g < 4; ++g) {
        const int c = n0 + colloc + g * 16;
        const float b = bias[c];
#pragma unroll
        for (int r = 0; r < 4; ++r) {
          const int row = m0 + rowb + f * 16 + r;
          H[(size_t)row * N + c] = f2bf(fmaxf(acc[f][g][r] + b, 0.f));
        }
      }
  } else {
    float* O = (float*)OutP;
#pragma unroll
    for (int f = 0; f < 8; ++f)
#pragma unroll
      for (int g = 0; g < 4; ++g) {
        const int c = n0 + colloc + g * 16;
        const float b = bias[c];
#pragma unroll
        for (int r = 0; r < 4; ++r) {
          const int row = m0 + rowb + f * 16 + r;
          O[(size_t)row * N + c] = (acc[f][g][r] + b) * wrow[row];
        }
      }
  }
#undef STAGE
}

extern "C" void kernel_launch(void* const* d_in, const int* in_sizes, int n_in,
                              void* d_out, int out_size, void* d_ws, size_t ws_size,
                              hipStream_t stream) {
  const float* u    = (const float*)d_in[0];
  const float* v    = (const float*)d_in[1];
  const float* u_W1 = (const float*)d_in[2];
  const float* u_b1 = (const float*)d_in[3];
  const float* u_W2 = (const float*)d_in[4];
  const float* u_b2 = (const float*)d_in[5];
  const float* v_W1 = (const float*)d_in[6];
  const float* v_b1 = (const float*)d_in[7];
  const float* v_W2 = (const float*)d_in[8];
  const float* v_b2 = (const float*)d_in[9];
  float* out1 = (float*)d_out;
  float* out2 = out1 + (size_t)NROWS * XD;

  float* wsf = (float*)d_ws;
  size_t off = 0;
  float* w_     = wsf + off; off += NROWS;
  float* kv     = wsf + off; off += 16;
  float* u_mean = wsf + off; off += XD;
  float* u_inv  = wsf + off; off += XD;
  float* v_mean = wsf + off; off += DD;
  float* v_inv  = wsf + off; off += DD;
  float* p1u    = wsf + off; off += 64 * XD;
  float* p2u    = wsf + off; off += 64 * XD;
  float* p1v    = wsf + off; off += 64 * DD;
  float* p2v    = wsf + off; off += 64 * DD;

  size_t boff = (off * 4 + 255) & ~(size_t)255;
  unsigned short* W1Tu = (unsigned short*)((char*)d_ws + boff); boff += (size_t)(2 * XD) * XD * 2;
  unsigned short* W2Tu = (unsigned short*)((char*)d_ws + boff); boff += (size_t)XD * (2 * XD) * 2;
  unsigned short* W1Tv = (unsigned short*)((char*)d_ws + boff); boff += (size_t)(2 * DD) * DD * 2;
  unsigned short* W2Tv = (unsigned short*)((char*)d_ws + boff); boff += (size_t)DD * (2 * DD) * 2;
  size_t fixedB = (boff + 255) & ~(size_t)255;

  // choose chunk sizes by fit + grid-utilization cost
  static const int chs[7] = {16384, 8192, 4096, 2048, 1024, 512, 256};
  int CHu = 256, CHv = 256;
  double best = 1e30;
  for (int a = 0; a < 7; ++a)
    for (int b = 0; b < 7; ++b) {
      int cu = chs[a], cv = chs[b];
      size_t need = fixedB + (size_t)cu * XD * 6 + (size_t)cv * DD * 6 + 1024;
      if (need > ws_size) continue;
      auto util = [](int nwg) { return nwg >= 256 ? 1.0 : nwg / 256.0; };
      double cost = 68.75 / util((cu >> 8) * 8) + 68.75 / util((cu >> 8) * 4) +
                    550.0 / util((cv >> 8) * 32) + 550.0 / util((cv >> 8) * 16);
      if (cost < best) { best = cost; CHu = cu; CHv = cv; }
    }

  size_t p = fixedB;
  unsigned short* unc  = (unsigned short*)((char*)d_ws + p); p += (size_t)CHu * XD * 2;
  unsigned short* uhid = (unsigned short*)((char*)d_ws + p); p += (size_t)CHu * (2 * XD) * 2;
  unsigned short* vnc  = (unsigned short*)((char*)d_ws + p); p += (size_t)CHv * DD * 2;
  unsigned short* vhid = (unsigned short*)((char*)d_ws + p);

  // ---- stats ----
  mask_kernel<<<NROWS, 256, 0, stream>>>(u, v, w_);
  ksum_kernel<<<1, 256, 0, stream>>>(w_, kv);
  colstats_partial<<<dim3(XD / 256, 64), 256, 0, stream>>>(u, XD, w_, p1u, p2u);
  colstats_partial<<<dim3(DD / 256, 64), 256, 0, stream>>>(v, DD, w_, p1v, p2v);
  colstats_final<<<XD / 256, 256, 0, stream>>>(p1u, p2u, kv, XD, u_mean, u_inv);
  colstats_final<<<DD / 256, 256, 0, stream>>>(p1v, p2v, kv, DD, v_mean, v_inv);

  // ---- weights -> bf16 transposed ----
  wt_kernel<<<dim3(XD / 64, (2 * XD) / 64), 256, 0, stream>>>(u_W1, XD, 2 * XD, W1Tu);
  wt_kernel<<<dim3((2 * XD) / 64, XD / 64), 256, 0, stream>>>(u_W2, 2 * XD, XD, W2Tu);
  wt_kernel<<<dim3(DD / 64, (2 * DD) / 64), 256, 0, stream>>>(v_W1, DD, 2 * DD, W1Tv);
  wt_kernel<<<dim3((2 * DD) / 64, DD / 64), 256, 0, stream>>>(v_W2, 2 * DD, DD, W2Tv);

  // ---- u path ----
  for (int r0 = 0; r0 < NROWS; r0 += CHu) {
    size_t n8 = (size_t)CHu * XD / 8;
    int ng = (int)(n8 / 256 < 2048 ? n8 / 256 : 2048);
    norm_kernel<<<ng, 256, 0, stream>>>(u + (size_t)r0 * XD, u_mean, u_inv, unc, XD / 8 - 1, n8);
    gemm8p<0><<<(CHu >> 8) * ((2 * XD) >> 8), 512, 0, stream>>>(unc, W1Tu, u_b1, nullptr, uhid,
                                                                2 * XD, XD);
    gemm8p<1><<<(CHu >> 8) * (XD >> 8), 512, 0, stream>>>(uhid, W2Tu, u_b2, w_ + r0,
                                                          out1 + (size_t)r0 * XD, XD, 2 * XD);
  }
  // ---- v path ----
  for (int r0 = 0; r0 < NROWS; r0 += CHv) {
    size_t n8 = (size_t)CHv * DD / 8;
    int ng = (int)(n8 / 256 < 2048 ? n8 / 256 : 2048);
    norm_kernel<<<ng, 256, 0, stream>>>(v + (size_t)r0 * DD, v_mean, v_inv, vnc, DD / 8 - 1, n8);
    gemm8p<0><<<(CHv >> 8) * ((2 * DD) >> 8), 512, 0, stream>>>(vnc, W1Tv, v_b1, nullptr, vhid,
                                                                2 * DD, DD);
    gemm8p<1><<<(CHv >> 8) * (DD >> 8), 512, 0, stream>>>(vhid, W2Tv, v_b2, w_ + r0,
                                                          out2 + (size_t)r0 * DD, DD, 2 * DD);
  }
}